// Round 8
// baseline (220.206 us; speedup 1.0000x reference)
//
#include <hip/hip_runtime.h>
#include <math.h>

#define N_NODES 50000
#define N_EDGES 800000
#define D 64

#define NB 256                    // dst buckets
#define NBLK 256                  // blocks in bucket hist/scatter
#define BUCKET_NODES 196          // ceil(50000/256); 256*196 = 50176
#define TILE 3125                 // 800000 / 256 exactly

typedef unsigned short ushort_t;

__device__ __forceinline__ ushort_t f32_to_bf16(float f) {
    unsigned u = __float_as_uint(f);
    u += 0x7fffu + ((u >> 16) & 1u);      // round-to-nearest-even
    return (ushort_t)(u >> 16);
}

// ============================================================
// Generic 3-phase exclusive scan (1024 elems/block)
// ============================================================
template<int N>
__global__ void scan_partial_g(const int* __restrict__ in, int* __restrict__ partials) {
    const int base = blockIdx.x * 1024 + threadIdx.x * 4;
    int4 c = make_int4(0, 0, 0, 0);
    if (base + 3 < N) c = *(const int4*)&in[base];
    else { int* cp = (int*)&c; for (int j = 0; j < 4; ++j) if (base + j < N) cp[j] = in[base + j]; }
    int s = c.x + c.y + c.z + c.w;
    #pragma unroll
    for (int off = 32; off >= 1; off >>= 1) s += __shfl_xor(s, off, 64);
    __shared__ int red[4];
    if ((threadIdx.x & 63) == 0) red[threadIdx.x >> 6] = s;
    __syncthreads();
    if (threadIdx.x == 0) partials[blockIdx.x] = red[0] + red[1] + red[2] + red[3];
}

__global__ void scan_offsets_g(int* __restrict__ partials, int nt, int* __restrict__ total_out) {
    const int lane = threadIdx.x;
    const int v = (lane < nt) ? partials[lane] : 0;
    int inc = v;
    #pragma unroll
    for (int off = 1; off < 64; off <<= 1) {
        const int w = __shfl_up(inc, off, 64);
        if (lane >= off) inc += w;
    }
    if (lane < nt) partials[lane] = inc - v;
    if (total_out != nullptr && lane == 63) *total_out = inc;
}

template<int N>
__global__ void scan_write_g(const int* __restrict__ in, const int* __restrict__ partials,
                             int* __restrict__ out) {
    const int tid  = threadIdx.x;
    const int base = blockIdx.x * 1024 + tid * 4;
    int4 c = make_int4(0, 0, 0, 0);
    if (base + 3 < N) c = *(const int4*)&in[base];
    else { int* cp = (int*)&c; for (int j = 0; j < 4; ++j) if (base + j < N) cp[j] = in[base + j]; }
    const int s = c.x + c.y + c.z + c.w;
    __shared__ int sh[256];
    sh[tid] = s;
    __syncthreads();
    for (int off = 1; off < 256; off <<= 1) {
        const int w = (tid >= off) ? sh[tid - off] : 0;
        __syncthreads();
        sh[tid] += w;
        __syncthreads();
    }
    int run = partials[blockIdx.x] + sh[tid] - s;
    const int* cp = (const int*)&c;
    int rp[4];
    #pragma unroll
    for (int j = 0; j < 4; ++j) { rp[j] = run; run += cp[j]; }
    if (base + 3 < N) *(int4*)&out[base] = make_int4(rp[0], rp[1], rp[2], rp[3]);
    else for (int j = 0; j < 4; ++j) if (base + j < N) out[base + j] = rp[j];
}

// ============================================================
// Bucketed CSR build — no global atomics, XCD-local final writes
// ============================================================
__global__ __launch_bounds__(256) void bucket_hist(const int* __restrict__ dst,
                                                   int* __restrict__ Acnt) {
    __shared__ int hist[NB];
    for (int i = threadIdx.x; i < NB; i += 256) hist[i] = 0;
    __syncthreads();
    const int base = blockIdx.x * TILE;
    for (int i = threadIdx.x; i < TILE; i += 256)
        atomicAdd(&hist[dst[base + i] / BUCKET_NODES], 1);
    __syncthreads();
    for (int bk = threadIdx.x; bk < NB; bk += 256)
        Acnt[bk * NBLK + blockIdx.x] = hist[bk];
}

__global__ __launch_bounds__(256) void bucket_scatter(const int* __restrict__ src,
                                                      const int* __restrict__ dst,
                                                      const int* __restrict__ offs,
                                                      int2* __restrict__ staging) {
    __shared__ int cur[NB];
    for (int i = threadIdx.x; i < NB; i += 256) cur[i] = offs[i * NBLK + blockIdx.x];
    __syncthreads();
    const int base = blockIdx.x * TILE;
    for (int i = threadIdx.x; i < TILE; i += 256) {
        const int s = src[base + i], d = dst[base + i];
        const int pos = atomicAdd(&cur[d / BUCKET_NODES], 1);
        staging[pos] = make_int2(s, d);
    }
}

__global__ __launch_bounds__(256) void node_counts(const int2* __restrict__ staging,
                                                   const int* __restrict__ offs,
                                                   int* __restrict__ counts) {
    __shared__ int cnt[BUCKET_NODES];
    const int b = blockIdx.x;
    for (int i = threadIdx.x; i < BUCKET_NODES; i += 256) cnt[i] = 0;
    __syncthreads();
    const int s0 = offs[b * NBLK];
    const int s1 = (b == NB - 1) ? N_EDGES : offs[(b + 1) * NBLK];
    for (int i = s0 + threadIdx.x; i < s1; i += 256)
        atomicAdd(&cnt[staging[i].y - b * BUCKET_NODES], 1);
    __syncthreads();
    for (int i = threadIdx.x; i < BUCKET_NODES; i += 256) {
        const int node = b * BUCKET_NODES + i;
        if (node < N_NODES) counts[node] = cnt[i];
    }
}

__global__ __launch_bounds__(256) void bucket_to_csr(const int2* __restrict__ staging,
                                                     const int* __restrict__ offs,
                                                     const int* __restrict__ row_ptr,
                                                     int* __restrict__ csr_src) {
    __shared__ int cur[BUCKET_NODES];
    const int b = blockIdx.x;
    for (int i = threadIdx.x; i < BUCKET_NODES; i += 256) {
        const int node = b * BUCKET_NODES + i;
        cur[i] = (node < N_NODES) ? row_ptr[node] : 0;
    }
    __syncthreads();
    const int s0 = offs[b * NBLK];
    const int s1 = (b == NB - 1) ? N_EDGES : offs[(b + 1) * NBLK];
    for (int i = s0 + threadIdx.x; i < s1; i += 256) {
        const int2 e = staging[i];
        const int pos = atomicAdd(&cur[e.y - b * BUCKET_NODES], 1);
        csr_src[pos] = e.x;
    }
}

// ---- fallback CSR build (used only if ws too small) ----
__global__ void hist_kernel(const int* __restrict__ dst, int* __restrict__ counts) {
    const int i = blockIdx.x * blockDim.x + threadIdx.x;
    if (i < N_EDGES) atomicAdd(&counts[dst[i]], 1);
}
__global__ void copy_kernel(const int* __restrict__ in, int* __restrict__ out, int n) {
    const int i = blockIdx.x * blockDim.x + threadIdx.x;
    if (i < n) out[i] = in[i];
}
__global__ void scatter_kernel(const int* __restrict__ src, const int* __restrict__ dst,
                               int* __restrict__ cursor, int* __restrict__ csr_src) {
    const int i = blockIdx.x * blockDim.x + threadIdx.x;
    if (i >= N_EDGES) return;
    const int pos = atomicAdd(&cursor[dst[i]], 1);
    csr_src[pos] = src[i];
}

// ============================================================
// K1: z = h @ W.T + b — wave owns 8 rows, lane = output column.
//     z stored as bf16 (halves aggregate-gather traffic).
// ============================================================
#define NL_ROWS 8
__global__ __launch_bounds__(256) void node_linear_gemm(
    const float* __restrict__ h, ushort_t* __restrict__ zb,
    const float* __restrict__ W, const float* __restrict__ b,
    const float* __restrict__ a, const float* __restrict__ ab,
    float* __restrict__ s_src, float* __restrict__ s_dst)
{
    __shared__ float Wt[64 * 65];           // Wt[k*65 + j] = W[j*64 + k]
    for (int idx = threadIdx.x; idx < D * D; idx += 256) {
        const int j = idx >> 6, k = idx & 63;
        Wt[k * 65 + j] = W[idx];
    }
    __syncthreads();

    const int lane = threadIdx.x & 63;
    const int wv   = __builtin_amdgcn_readfirstlane(threadIdx.x >> 6);
    const int row0 = (blockIdx.x * 4 + wv) * NL_ROWS;
    if (row0 >= N_NODES) return;

    const float bj  = b[lane];
    const float alo = a[lane];
    const float ahi = a[64 + lane];

    const float* hr[NL_ROWS];
    #pragma unroll
    for (int r = 0; r < NL_ROWS; ++r) hr[r] = h + (size_t)(row0 + r) * D;

    float acc[NL_ROWS];
    #pragma unroll
    for (int r = 0; r < NL_ROWS; ++r) acc[r] = bj;

    #pragma unroll 4
    for (int k = 0; k < D; ++k) {
        const float wkj = Wt[k * 65 + lane];
        #pragma unroll
        for (int r = 0; r < NL_ROWS; ++r)
            acc[r] = fmaf(hr[r][k], wkj, acc[r]);
    }

    #pragma unroll
    for (int r = 0; r < NL_ROWS; ++r) {
        zb[(size_t)(row0 + r) * D + lane] = f32_to_bf16(acc[r]);
        float u = acc[r] * alo;
        float v = acc[r] * ahi;
        #pragma unroll
        for (int off = 32; off >= 1; off >>= 1) {
            u += __shfl_xor(u, off, 64);
            v += __shfl_xor(v, off, 64);
        }
        if (lane == 0) { s_src[row0 + r] = u; s_dst[row0 + r] = v + ab[0]; }
    }
}

// ============================================================
// K2: fused per-dst softmax + aggregate + normalize (+ReLU).
//     bf16 z rows (128 B): one wave-load gathers TWO edge rows
//     (lanes 0-31 even edge, 32-63 odd edge; lane = feature pair).
//     16 edges (8 paired gathers) in flight per iteration.
// ============================================================
template<bool RELU>
__global__ __launch_bounds__(256) void gat_aggregate(
    const int* __restrict__ row_ptr, const int* __restrict__ csr_src,
    const float* __restrict__ s_src, const float* __restrict__ s_dst,
    const ushort_t* __restrict__ zb, float* __restrict__ out)
{
    __shared__ float sh_ex[4][64];
    __shared__ int   sh_si[4][64];
    const int lane = threadIdx.x & 63;
    const int wv   = threadIdx.x >> 6;
    const int node = blockIdx.x * 4 + wv;
    if (node >= N_NODES) return;
    const int beg = row_ptr[node];
    const int end = row_ptr[node + 1];
    if (beg == end) { out[(size_t)node * D + lane] = 0.f; return; }
    const int half = lane >> 5;          // 0: even-indexed edges, 1: odd
    const int fl   = lane & 31;          // feature-pair index (features 2fl, 2fl+1)
    const float sd = s_dst[node];

    float m = -INFINITY;
    float den = 0.f;
    float2 acc[8];
    #pragma unroll
    for (int p = 0; p < 8; ++p) acc[p] = make_float2(0.f, 0.f);

    for (int base = beg; base < end; base += 64) {
        const int n = min(64, end - base);
        const int sidx = (lane < n) ? csr_src[base + lane] : 0;
        float e = -INFINITY;
        if (lane < n) {
            e = s_src[sidx] + sd;
            e = e > 0.f ? e : 0.01f * e;          // leaky_relu
        }
        float mc = e;
        #pragma unroll
        for (int off = 32; off >= 1; off >>= 1) mc = fmaxf(mc, __shfl_xor(mc, off, 64));
        if (mc > m) {                              // online rescale
            const float scale = __expf(m - mc);
            den *= scale;
            #pragma unroll
            for (int p = 0; p < 8; ++p) { acc[p].x *= scale; acc[p].y *= scale; }
            m = mc;
        }
        const float ex = __expf(e - m);            // 0 for pad lanes (e = -inf)
        den += ex;
        sh_ex[wv][lane] = ex;
        sh_si[wv][lane] = sidx;                    // pad: sidx 0, weight 0
        for (int t = 0; t < n; t += 16) {
            #pragma unroll
            for (int p = 0; p < 8; ++p) {
                const int ei = t + 2 * p + half;   // <= 63 always
                const float w = sh_ex[wv][ei];
                const int   s = sh_si[wv][ei];
                const unsigned u = *(const unsigned*)&zb[(size_t)s * D + 2 * fl];
                const float f0 = __uint_as_float(u << 16);           // feature 2fl
                const float f1 = __uint_as_float(u & 0xffff0000u);   // feature 2fl+1
                acc[p].x = fmaf(w, f0, acc[p].x);
                acc[p].y = fmaf(w, f1, acc[p].y);
            }
        }
    }
    #pragma unroll
    for (int off = 32; off >= 1; off >>= 1) den += __shfl_xor(den, off, 64);
    float2 tot = make_float2(0.f, 0.f);
    #pragma unroll
    for (int p = 0; p < 8; ++p) { tot.x += acc[p].x; tot.y += acc[p].y; }
    tot.x += __shfl_xor(tot.x, 32, 64);            // merge odd/even halves
    tot.y += __shfl_xor(tot.y, 32, 64);
    float2 v = make_float2(tot.x / den, tot.y / den);
    if (RELU) { v.x = fmaxf(v.x, 0.f); v.y = fmaxf(v.y, 0.f); }
    if (half == 0)
        *(float2*)&out[(size_t)node * D + 2 * fl] = v;   // lanes 0-31: 256 B row
}

// ============================================================
extern "C" void kernel_launch(void* const* d_in, const int* in_sizes, int n_in,
                              void* d_out, int out_size, void* d_ws, size_t ws_size,
                              hipStream_t stream) {
    const float* x   = (const float*)d_in[0];
    const int*   src = (const int*)d_in[1];
    const int*   dst = (const int*)d_in[2];
    float* out = (float*)d_out;

    // ---- workspace carve-out (256B-aligned slots) ----
    char* wp = (char*)d_ws;
    auto alloc = [&](size_t bytes) -> void* {
        void* p = (void*)wp;
        wp += (bytes + 255) & ~(size_t)255;
        return p;
    };
    ushort_t* zb    = (ushort_t*)alloc((size_t)N_NODES * D * sizeof(ushort_t));
    float* s_src   = (float*)alloc((size_t)N_NODES * sizeof(float));
    float* s_dst   = (float*)alloc((size_t)N_NODES * sizeof(float));
    int*   counts  = (int*)alloc((size_t)N_NODES * sizeof(int));
    int*   row_ptr = (int*)alloc((size_t)(N_NODES + 1) * sizeof(int));
    int*   csr_src = (int*)alloc((size_t)N_EDGES * sizeof(int));
    int*   partA   = (int*)alloc(64 * sizeof(int));
    int*   partB   = (int*)alloc(64 * sizeof(int));
    int*   cursor  = (int*)alloc((size_t)N_NODES * sizeof(int));       // fallback only
    int*   Acnt    = (int*)alloc((size_t)NB * NBLK * sizeof(int));
    int*   offs    = (int*)alloc((size_t)NB * NBLK * sizeof(int));
    int2*  staging = (int2*)alloc((size_t)N_EDGES * sizeof(int2));
    size_t bucket_used = (size_t)(wp - (char*)d_ws);

    const bool use_bucket = (ws_size >= bucket_used);

    if (use_bucket) {
        // ---- bucketed CSR build: zero global atomics ----
        bucket_hist<<<NBLK, 256, 0, stream>>>(dst, Acnt);
        scan_partial_g<NB * NBLK><<<64, 256, 0, stream>>>(Acnt, partB);
        scan_offsets_g<<<1, 64, 0, stream>>>(partB, 64, nullptr);
        scan_write_g<NB * NBLK><<<64, 256, 0, stream>>>(Acnt, partB, offs);
        bucket_scatter<<<NBLK, 256, 0, stream>>>(src, dst, offs, staging);
        node_counts<<<NB, 256, 0, stream>>>(staging, offs, counts);
        scan_partial_g<N_NODES><<<49, 256, 0, stream>>>(counts, partA);
        scan_offsets_g<<<1, 64, 0, stream>>>(partA, 49, &row_ptr[N_NODES]);
        scan_write_g<N_NODES><<<49, 256, 0, stream>>>(counts, partA, row_ptr);
        bucket_to_csr<<<NB, 256, 0, stream>>>(staging, offs, row_ptr, csr_src);
    } else {
        // ---- fallback: atomic scatter path ----
        hipMemsetAsync(counts, 0, (size_t)N_NODES * sizeof(int), stream);
        hist_kernel<<<(N_EDGES + 255) / 256, 256, 0, stream>>>(dst, counts);
        scan_partial_g<N_NODES><<<49, 256, 0, stream>>>(counts, partA);
        scan_offsets_g<<<1, 64, 0, stream>>>(partA, 49, &row_ptr[N_NODES]);
        scan_write_g<N_NODES><<<49, 256, 0, stream>>>(counts, partA, row_ptr);
        copy_kernel<<<(N_NODES + 255) / 256, 256, 0, stream>>>(row_ptr, cursor, N_NODES);
        scatter_kernel<<<(N_EDGES + 255) / 256, 256, 0, stream>>>(src, dst, cursor, csr_src);
    }

    const int grid_k1  = (N_NODES + 4 * NL_ROWS - 1) / (4 * NL_ROWS);  // 1563
    const int grid_agg = (N_NODES + 3) / 4;                            // 12500

    for (int layer = 0; layer < 3; ++layer) {
        const float* W  = (const float*)d_in[3 + 4 * layer];
        const float* b  = (const float*)d_in[4 + 4 * layer];
        const float* a  = (const float*)d_in[5 + 4 * layer];
        const float* ab = (const float*)d_in[6 + 4 * layer];
        const float* hin = (layer == 0) ? x : out;   // d_out doubles as h buffer

        node_linear_gemm<<<grid_k1, 256, 0, stream>>>(hin, zb, W, b, a, ab, s_src, s_dst);
        if (layer < 2) {
            gat_aggregate<true ><<<grid_agg, 256, 0, stream>>>(row_ptr, csr_src, s_src, s_dst, zb, out);
        } else {
            gat_aggregate<false><<<grid_agg, 256, 0, stream>>>(row_ptr, csr_src, s_src, s_dst, zb, out);
        }
    }
}

// Round 9
// 210.844 us; speedup vs baseline: 1.0444x; 1.0444x over previous
//
#include <hip/hip_runtime.h>
#include <math.h>

#define N_NODES 50000
#define N_EDGES 800000
#define D 64

#define NB 256                    // dst buckets
#define NBLK 256                  // blocks in bucket hist/scatter
#define BUCKET_NODES 196          // ceil(50000/256); 256*196 = 50176
#define TILE 3125                 // 800000 / 256 exactly

typedef unsigned short ushort_t;

__device__ __forceinline__ ushort_t f32_to_bf16(float f) {
    unsigned u = __float_as_uint(f);
    u += 0x7fffu + ((u >> 16) & 1u);      // round-to-nearest-even
    return (ushort_t)(u >> 16);
}

// ============================================================
// Generic 3-phase exclusive scan (1024 elems/block)
// ============================================================
template<int N>
__global__ void scan_partial_g(const int* __restrict__ in, int* __restrict__ partials) {
    const int base = blockIdx.x * 1024 + threadIdx.x * 4;
    int4 c = make_int4(0, 0, 0, 0);
    if (base + 3 < N) c = *(const int4*)&in[base];
    else { int* cp = (int*)&c; for (int j = 0; j < 4; ++j) if (base + j < N) cp[j] = in[base + j]; }
    int s = c.x + c.y + c.z + c.w;
    #pragma unroll
    for (int off = 32; off >= 1; off >>= 1) s += __shfl_xor(s, off, 64);
    __shared__ int red[4];
    if ((threadIdx.x & 63) == 0) red[threadIdx.x >> 6] = s;
    __syncthreads();
    if (threadIdx.x == 0) partials[blockIdx.x] = red[0] + red[1] + red[2] + red[3];
}

__global__ void scan_offsets_g(int* __restrict__ partials, int nt, int* __restrict__ total_out) {
    const int lane = threadIdx.x;
    const int v = (lane < nt) ? partials[lane] : 0;
    int inc = v;
    #pragma unroll
    for (int off = 1; off < 64; off <<= 1) {
        const int w = __shfl_up(inc, off, 64);
        if (lane >= off) inc += w;
    }
    if (lane < nt) partials[lane] = inc - v;
    if (total_out != nullptr && lane == 63) *total_out = inc;
}

template<int N>
__global__ void scan_write_g(const int* __restrict__ in, const int* __restrict__ partials,
                             int* __restrict__ out) {
    const int tid  = threadIdx.x;
    const int base = blockIdx.x * 1024 + tid * 4;
    int4 c = make_int4(0, 0, 0, 0);
    if (base + 3 < N) c = *(const int4*)&in[base];
    else { int* cp = (int*)&c; for (int j = 0; j < 4; ++j) if (base + j < N) cp[j] = in[base + j]; }
    const int s = c.x + c.y + c.z + c.w;
    __shared__ int sh[256];
    sh[tid] = s;
    __syncthreads();
    for (int off = 1; off < 256; off <<= 1) {
        const int w = (tid >= off) ? sh[tid - off] : 0;
        __syncthreads();
        sh[tid] += w;
        __syncthreads();
    }
    int run = partials[blockIdx.x] + sh[tid] - s;
    const int* cp = (const int*)&c;
    int rp[4];
    #pragma unroll
    for (int j = 0; j < 4; ++j) { rp[j] = run; run += cp[j]; }
    if (base + 3 < N) *(int4*)&out[base] = make_int4(rp[0], rp[1], rp[2], rp[3]);
    else for (int j = 0; j < 4; ++j) if (base + j < N) out[base + j] = rp[j];
}

// ============================================================
// Bucketed CSR build — no global atomics, XCD-local final writes
// ============================================================
__global__ __launch_bounds__(256) void bucket_hist(const int* __restrict__ dst,
                                                   int* __restrict__ Acnt) {
    __shared__ int hist[NB];
    for (int i = threadIdx.x; i < NB; i += 256) hist[i] = 0;
    __syncthreads();
    const int base = blockIdx.x * TILE;
    for (int i = threadIdx.x; i < TILE; i += 256)
        atomicAdd(&hist[dst[base + i] / BUCKET_NODES], 1);
    __syncthreads();
    for (int bk = threadIdx.x; bk < NB; bk += 256)
        Acnt[bk * NBLK + blockIdx.x] = hist[bk];
}

__global__ __launch_bounds__(256) void bucket_scatter(const int* __restrict__ src,
                                                      const int* __restrict__ dst,
                                                      const int* __restrict__ offs,
                                                      int2* __restrict__ staging) {
    __shared__ int cur[NB];
    for (int i = threadIdx.x; i < NB; i += 256) cur[i] = offs[i * NBLK + blockIdx.x];
    __syncthreads();
    const int base = blockIdx.x * TILE;
    for (int i = threadIdx.x; i < TILE; i += 256) {
        const int s = src[base + i], d = dst[base + i];
        const int pos = atomicAdd(&cur[d / BUCKET_NODES], 1);
        staging[pos] = make_int2(s, d);
    }
}

__global__ __launch_bounds__(256) void node_counts(const int2* __restrict__ staging,
                                                   const int* __restrict__ offs,
                                                   int* __restrict__ counts) {
    __shared__ int cnt[BUCKET_NODES];
    const int b = blockIdx.x;
    for (int i = threadIdx.x; i < BUCKET_NODES; i += 256) cnt[i] = 0;
    __syncthreads();
    const int s0 = offs[b * NBLK];
    const int s1 = (b == NB - 1) ? N_EDGES : offs[(b + 1) * NBLK];
    for (int i = s0 + threadIdx.x; i < s1; i += 256)
        atomicAdd(&cnt[staging[i].y - b * BUCKET_NODES], 1);
    __syncthreads();
    for (int i = threadIdx.x; i < BUCKET_NODES; i += 256) {
        const int node = b * BUCKET_NODES + i;
        if (node < N_NODES) counts[node] = cnt[i];
    }
}

__global__ __launch_bounds__(256) void bucket_to_csr(const int2* __restrict__ staging,
                                                     const int* __restrict__ offs,
                                                     const int* __restrict__ row_ptr,
                                                     int* __restrict__ csr_src) {
    __shared__ int cur[BUCKET_NODES];
    const int b = blockIdx.x;
    for (int i = threadIdx.x; i < BUCKET_NODES; i += 256) {
        const int node = b * BUCKET_NODES + i;
        cur[i] = (node < N_NODES) ? row_ptr[node] : 0;
    }
    __syncthreads();
    const int s0 = offs[b * NBLK];
    const int s1 = (b == NB - 1) ? N_EDGES : offs[(b + 1) * NBLK];
    for (int i = s0 + threadIdx.x; i < s1; i += 256) {
        const int2 e = staging[i];
        const int pos = atomicAdd(&cur[e.y - b * BUCKET_NODES], 1);
        csr_src[pos] = e.x;
    }
}

// ---- fallback CSR build (used only if ws too small) ----
__global__ void hist_kernel(const int* __restrict__ dst, int* __restrict__ counts) {
    const int i = blockIdx.x * blockDim.x + threadIdx.x;
    if (i < N_EDGES) atomicAdd(&counts[dst[i]], 1);
}
__global__ void copy_kernel(const int* __restrict__ in, int* __restrict__ out, int n) {
    const int i = blockIdx.x * blockDim.x + threadIdx.x;
    if (i < n) out[i] = in[i];
}
__global__ void scatter_kernel(const int* __restrict__ src, const int* __restrict__ dst,
                               int* __restrict__ cursor, int* __restrict__ csr_src) {
    const int i = blockIdx.x * blockDim.x + threadIdx.x;
    if (i >= N_EDGES) return;
    const int pos = atomicAdd(&cursor[dst[i]], 1);
    csr_src[pos] = src[i];
}

// ============================================================
// K1: z = h @ W.T + b — wave owns 8 rows, lane = output column.
//     z stored as bf16.
// ============================================================
#define NL_ROWS 8
__global__ __launch_bounds__(256) void node_linear_gemm(
    const float* __restrict__ h, ushort_t* __restrict__ zb,
    const float* __restrict__ W, const float* __restrict__ b,
    const float* __restrict__ a, const float* __restrict__ ab,
    float* __restrict__ s_src, float* __restrict__ s_dst)
{
    __shared__ float Wt[64 * 65];           // Wt[k*65 + j] = W[j*64 + k]
    for (int idx = threadIdx.x; idx < D * D; idx += 256) {
        const int j = idx >> 6, k = idx & 63;
        Wt[k * 65 + j] = W[idx];
    }
    __syncthreads();

    const int lane = threadIdx.x & 63;
    const int wv   = __builtin_amdgcn_readfirstlane(threadIdx.x >> 6);
    const int row0 = (blockIdx.x * 4 + wv) * NL_ROWS;
    if (row0 >= N_NODES) return;

    const float bj  = b[lane];
    const float alo = a[lane];
    const float ahi = a[64 + lane];

    const float* hr[NL_ROWS];
    #pragma unroll
    for (int r = 0; r < NL_ROWS; ++r) hr[r] = h + (size_t)(row0 + r) * D;

    float acc[NL_ROWS];
    #pragma unroll
    for (int r = 0; r < NL_ROWS; ++r) acc[r] = bj;

    #pragma unroll 4
    for (int k = 0; k < D; ++k) {
        const float wkj = Wt[k * 65 + lane];
        #pragma unroll
        for (int r = 0; r < NL_ROWS; ++r)
            acc[r] = fmaf(hr[r][k], wkj, acc[r]);
    }

    #pragma unroll
    for (int r = 0; r < NL_ROWS; ++r) {
        zb[(size_t)(row0 + r) * D + lane] = f32_to_bf16(acc[r]);
        float u = acc[r] * alo;
        float v = acc[r] * ahi;
        #pragma unroll
        for (int off = 32; off >= 1; off >>= 1) {
            u += __shfl_xor(u, off, 64);
            v += __shfl_xor(v, off, 64);
        }
        if (lane == 0) { s_src[row0 + r] = u; s_dst[row0 + r] = v + ab[0]; }
    }
}

// ============================================================
// K2a: edge softmax — 4 nodes per wave, 16 lanes per node.
//      Writes NORMALIZED weight packed with src: wgtsi = (w, src).
// ============================================================
__global__ __launch_bounds__(256) void edge_softmax(
    const int* __restrict__ row_ptr, const int* __restrict__ csr_src,
    const float* __restrict__ s_src, const float* __restrict__ s_dst,
    float* __restrict__ raw, int2* __restrict__ wgtsi)
{
    const int lane = threadIdx.x & 63;
    const int sl   = lane & 15;                 // slot within node group
    const int g    = lane >> 4;                 // node group 0..3
    const int wid  = blockIdx.x * 4 + (threadIdx.x >> 6);
    const int node = wid * 4 + g;
    if (node >= N_NODES) return;
    const int beg = row_ptr[node];
    const int end = row_ptr[node + 1];
    if (beg == end) return;
    const float sd = s_dst[node];

    float m = -INFINITY, den = 0.f;             // group-uniform
    for (int base = beg; base < end; base += 16) {
        const int n = min(16, end - base);
        float e = -INFINITY;
        if (sl < n) {
            const int s = csr_src[base + sl];
            e = s_src[s] + sd;
            e = e > 0.f ? e : 0.01f * e;        // leaky_relu
            raw[base + sl] = e;
        }
        float mc = e;
        #pragma unroll
        for (int off = 8; off >= 1; off >>= 1) mc = fmaxf(mc, __shfl_xor(mc, off, 64));
        if (mc > m) { den *= __expf(m - mc); m = mc; }
        float ex = (sl < n) ? __expf(e - m) : 0.f;
        #pragma unroll
        for (int off = 8; off >= 1; off >>= 1) ex += __shfl_xor(ex, off, 64);
        den += ex;
    }
    const float inv = 1.f / den;
    for (int base = beg; base < end; base += 16) {
        const int n = min(16, end - base);
        if (sl < n) {
            const int i = base + sl;            // raw[i] written by THIS thread above
            const float w = __expf(raw[i] - m) * inv;
            wgtsi[i] = make_int2(__float_as_int(w), csr_src[i]);
        }
    }
}

// ============================================================
// K2b: weighted gather-sum — one wave per node, no softmax math.
//      bf16 z rows: lanes 0-31 even edge, 32-63 odd edge.
// ============================================================
template<bool RELU>
__global__ __launch_bounds__(256) void weighted_gather(
    const int* __restrict__ row_ptr, const int2* __restrict__ wgtsi,
    const ushort_t* __restrict__ zb, float* __restrict__ out)
{
    __shared__ int2 sh[4][64];
    const int lane = threadIdx.x & 63;
    const int wv   = threadIdx.x >> 6;
    const int node = blockIdx.x * 4 + wv;
    if (node >= N_NODES) return;
    const int beg = row_ptr[node];
    const int end = row_ptr[node + 1];
    const int half = lane >> 5;          // 0: even edges, 1: odd edges
    const int fl   = lane & 31;          // feature pair (2fl, 2fl+1)

    float2 acc[8];
    #pragma unroll
    for (int p = 0; p < 8; ++p) acc[p] = make_float2(0.f, 0.f);

    for (int base = beg; base < end; base += 64) {
        const int n = min(64, end - base);
        sh[wv][lane] = (lane < n) ? wgtsi[base + lane] : make_int2(0, 0);
        for (int t = 0; t < n; t += 16) {
            #pragma unroll
            for (int p = 0; p < 8; ++p) {
                const int ei = t + 2 * p + half;
                const int2 ws = sh[wv][ei];
                const float w = __int_as_float(ws.x);    // 0 for pad slots
                const unsigned u = *(const unsigned*)&zb[(size_t)ws.y * D + 2 * fl];
                acc[p].x = fmaf(w, __uint_as_float(u << 16), acc[p].x);
                acc[p].y = fmaf(w, __uint_as_float(u & 0xffff0000u), acc[p].y);
            }
        }
    }
    float2 tot = make_float2(0.f, 0.f);
    #pragma unroll
    for (int p = 0; p < 8; ++p) { tot.x += acc[p].x; tot.y += acc[p].y; }
    tot.x += __shfl_xor(tot.x, 32, 64);
    tot.y += __shfl_xor(tot.y, 32, 64);
    if (RELU) { tot.x = fmaxf(tot.x, 0.f); tot.y = fmaxf(tot.y, 0.f); }
    if (half == 0)
        *(float2*)&out[(size_t)node * D + 2 * fl] = tot;
}

// ============================================================
extern "C" void kernel_launch(void* const* d_in, const int* in_sizes, int n_in,
                              void* d_out, int out_size, void* d_ws, size_t ws_size,
                              hipStream_t stream) {
    const float* x   = (const float*)d_in[0];
    const int*   src = (const int*)d_in[1];
    const int*   dst = (const int*)d_in[2];
    float* out = (float*)d_out;

    // ---- workspace carve-out (256B-aligned slots) ----
    char* wp = (char*)d_ws;
    auto alloc = [&](size_t bytes) -> void* {
        void* p = (void*)wp;
        wp += (bytes + 255) & ~(size_t)255;
        return p;
    };
    ushort_t* zb   = (ushort_t*)alloc((size_t)N_NODES * D * sizeof(ushort_t));
    float* s_src   = (float*)alloc((size_t)N_NODES * sizeof(float));
    float* s_dst   = (float*)alloc((size_t)N_NODES * sizeof(float));
    int*   counts  = (int*)alloc((size_t)N_NODES * sizeof(int));
    int*   row_ptr = (int*)alloc((size_t)(N_NODES + 1) * sizeof(int));
    int*   csr_src = (int*)alloc((size_t)N_EDGES * sizeof(int));
    int*   partA   = (int*)alloc(64 * sizeof(int));
    int*   partB   = (int*)alloc(64 * sizeof(int));
    float* raw     = (float*)alloc((size_t)N_EDGES * sizeof(float));
    int2*  wgtsi   = (int2*)alloc((size_t)N_EDGES * sizeof(int2));
    int*   cursor  = (int*)alloc((size_t)N_NODES * sizeof(int));       // fallback only
    int*   Acnt    = (int*)alloc((size_t)NB * NBLK * sizeof(int));
    int*   offs    = (int*)alloc((size_t)NB * NBLK * sizeof(int));
    int2*  staging = (int2*)alloc((size_t)N_EDGES * sizeof(int2));
    size_t bucket_used = (size_t)(wp - (char*)d_ws);

    const bool use_bucket = (ws_size >= bucket_used);

    if (use_bucket) {
        // ---- bucketed CSR build: zero global atomics ----
        bucket_hist<<<NBLK, 256, 0, stream>>>(dst, Acnt);
        scan_partial_g<NB * NBLK><<<64, 256, 0, stream>>>(Acnt, partB);
        scan_offsets_g<<<1, 64, 0, stream>>>(partB, 64, nullptr);
        scan_write_g<NB * NBLK><<<64, 256, 0, stream>>>(Acnt, partB, offs);
        bucket_scatter<<<NBLK, 256, 0, stream>>>(src, dst, offs, staging);
        node_counts<<<NB, 256, 0, stream>>>(staging, offs, counts);
        scan_partial_g<N_NODES><<<49, 256, 0, stream>>>(counts, partA);
        scan_offsets_g<<<1, 64, 0, stream>>>(partA, 49, &row_ptr[N_NODES]);
        scan_write_g<N_NODES><<<49, 256, 0, stream>>>(counts, partA, row_ptr);
        bucket_to_csr<<<NB, 256, 0, stream>>>(staging, offs, row_ptr, csr_src);
    } else {
        // ---- fallback: atomic scatter path ----
        hipMemsetAsync(counts, 0, (size_t)N_NODES * sizeof(int), stream);
        hist_kernel<<<(N_EDGES + 255) / 256, 256, 0, stream>>>(dst, counts);
        scan_partial_g<N_NODES><<<49, 256, 0, stream>>>(counts, partA);
        scan_offsets_g<<<1, 64, 0, stream>>>(partA, 49, &row_ptr[N_NODES]);
        scan_write_g<N_NODES><<<49, 256, 0, stream>>>(counts, partA, row_ptr);
        copy_kernel<<<(N_NODES + 255) / 256, 256, 0, stream>>>(row_ptr, cursor, N_NODES);
        scatter_kernel<<<(N_EDGES + 255) / 256, 256, 0, stream>>>(src, dst, cursor, csr_src);
    }

    const int grid_k1  = (N_NODES + 4 * NL_ROWS - 1) / (4 * NL_ROWS);  // 1563
    const int grid_sm  = (N_NODES + 15) / 16;                          // 3125
    const int grid_agg = (N_NODES + 3) / 4;                            // 12500

    for (int layer = 0; layer < 3; ++layer) {
        const float* W  = (const float*)d_in[3 + 4 * layer];
        const float* b  = (const float*)d_in[4 + 4 * layer];
        const float* a  = (const float*)d_in[5 + 4 * layer];
        const float* ab = (const float*)d_in[6 + 4 * layer];
        const float* hin = (layer == 0) ? x : out;   // d_out doubles as h buffer

        node_linear_gemm<<<grid_k1, 256, 0, stream>>>(hin, zb, W, b, a, ab, s_src, s_dst);
        edge_softmax<<<grid_sm, 256, 0, stream>>>(row_ptr, csr_src, s_src, s_dst, raw, wgtsi);
        if (layer < 2) {
            weighted_gather<true ><<<grid_agg, 256, 0, stream>>>(row_ptr, wgtsi, zb, out);
        } else {
            weighted_gather<false><<<grid_agg, 256, 0, stream>>>(row_ptr, wgtsi, zb, out);
        }
    }
}

// Round 10
// 199.573 us; speedup vs baseline: 1.1034x; 1.0565x over previous
//
#include <hip/hip_runtime.h>
#include <math.h>

#define N_NODES 50000
#define N_EDGES 800000
#define D 64

#define NB 256                    // dst buckets
#define NBLK 256                  // blocks in bucket hist/scatter
#define BUCKET_NODES 196          // ceil(50000/256); 256*196 = 50176
#define TILE 3125                 // 800000 / 256 exactly

typedef unsigned short ushort_t;

__device__ __forceinline__ ushort_t f32_to_bf16(float f) {
    unsigned u = __float_as_uint(f);
    u += 0x7fffu + ((u >> 16) & 1u);      // round-to-nearest-even
    return (ushort_t)(u >> 16);
}

// ============================================================
// scan pass 1: per-1024-tile sums
// ============================================================
template<int N>
__global__ void scan_partial_g(const int* __restrict__ in, int* __restrict__ partials) {
    const int base = blockIdx.x * 1024 + threadIdx.x * 4;
    int4 c = make_int4(0, 0, 0, 0);
    if (base + 3 < N) c = *(const int4*)&in[base];
    else { int* cp = (int*)&c; for (int j = 0; j < 4; ++j) if (base + j < N) cp[j] = in[base + j]; }
    int s = c.x + c.y + c.z + c.w;
    #pragma unroll
    for (int off = 32; off >= 1; off >>= 1) s += __shfl_xor(s, off, 64);
    __shared__ int red[4];
    if ((threadIdx.x & 63) == 0) red[threadIdx.x >> 6] = s;
    __syncthreads();
    if (threadIdx.x == 0) partials[blockIdx.x] = red[0] + red[1] + red[2] + red[3];
}

// ============================================================
// scan pass 2 (fused): each block re-scans the <=64 raw partials
// in wave 0, then does its local scan + write. No middle kernel.
// ============================================================
template<int N, int NT>
__global__ void scan_write_i(const int* __restrict__ in, const int* __restrict__ partials_raw,
                             int* __restrict__ out) {
    __shared__ int toff;
    __shared__ int sh[256];
    const int tid = threadIdx.x;
    if (tid < 64) {
        const int v = (tid < NT) ? partials_raw[tid] : 0;
        int inc = v;
        #pragma unroll
        for (int off = 1; off < 64; off <<= 1) {
            const int w = __shfl_up(inc, off, 64);
            if (tid >= off) inc += w;
        }
        if (tid == blockIdx.x) toff = inc - v;   // exclusive tile offset (blockIdx < 64)
    }
    const int base = blockIdx.x * 1024 + tid * 4;
    int4 c = make_int4(0, 0, 0, 0);
    if (base + 3 < N) c = *(const int4*)&in[base];
    else { int* cp = (int*)&c; for (int j = 0; j < 4; ++j) if (base + j < N) cp[j] = in[base + j]; }
    const int s = c.x + c.y + c.z + c.w;
    sh[tid] = s;
    __syncthreads();
    for (int off = 1; off < 256; off <<= 1) {
        const int w = (tid >= off) ? sh[tid - off] : 0;
        __syncthreads();
        sh[tid] += w;
        __syncthreads();
    }
    int run = toff + sh[tid] - s;
    const int* cp = (const int*)&c;
    int rp[4];
    #pragma unroll
    for (int j = 0; j < 4; ++j) { rp[j] = run; run += cp[j]; }
    if (base + 3 < N) *(int4*)&out[base] = make_int4(rp[0], rp[1], rp[2], rp[3]);
    else for (int j = 0; j < 4; ++j) if (base + j < N) out[base + j] = rp[j];
}

// ============================================================
// Bucketed CSR build — no global atomics, XCD-local final writes
// ============================================================
__global__ __launch_bounds__(256) void bucket_hist(const int* __restrict__ dst,
                                                   int* __restrict__ Acnt) {
    __shared__ int hist[NB];
    for (int i = threadIdx.x; i < NB; i += 256) hist[i] = 0;
    __syncthreads();
    const int base = blockIdx.x * TILE;
    for (int i = threadIdx.x; i < TILE; i += 256)
        atomicAdd(&hist[dst[base + i] / BUCKET_NODES], 1);
    __syncthreads();
    for (int bk = threadIdx.x; bk < NB; bk += 256)
        Acnt[bk * NBLK + blockIdx.x] = hist[bk];
}

__global__ __launch_bounds__(256) void bucket_scatter(const int* __restrict__ src,
                                                      const int* __restrict__ dst,
                                                      const int* __restrict__ offs,
                                                      int2* __restrict__ staging) {
    __shared__ int cur[NB];
    for (int i = threadIdx.x; i < NB; i += 256) cur[i] = offs[i * NBLK + blockIdx.x];
    __syncthreads();
    const int base = blockIdx.x * TILE;
    for (int i = threadIdx.x; i < TILE; i += 256) {
        const int s = src[base + i], d = dst[base + i];
        const int pos = atomicAdd(&cur[d / BUCKET_NODES], 1);
        staging[pos] = make_int2(s, d);
    }
}

// node histogram per bucket (LDS) + per-bucket total
__global__ __launch_bounds__(256) void node_counts(const int2* __restrict__ staging,
                                                   const int* __restrict__ offs,
                                                   int* __restrict__ counts,
                                                   int* __restrict__ bucket_sum) {
    __shared__ int cnt[BUCKET_NODES];
    __shared__ int red[4];
    const int b = blockIdx.x, tid = threadIdx.x;
    for (int i = tid; i < BUCKET_NODES; i += 256) cnt[i] = 0;
    __syncthreads();
    const int s0 = offs[b * NBLK];
    const int s1 = (b == NB - 1) ? N_EDGES : offs[(b + 1) * NBLK];
    for (int i = s0 + tid; i < s1; i += 256)
        atomicAdd(&cnt[staging[i].y - b * BUCKET_NODES], 1);
    __syncthreads();
    for (int i = tid; i < BUCKET_NODES; i += 256) {
        const int node = b * BUCKET_NODES + i;
        if (node < N_NODES) counts[node] = cnt[i];
    }
    int s = (tid < BUCKET_NODES) ? cnt[tid] : 0;
    #pragma unroll
    for (int off = 32; off >= 1; off >>= 1) s += __shfl_xor(s, off, 64);
    if ((tid & 63) == 0) red[tid >> 6] = s;
    __syncthreads();
    if (tid == 0) bucket_sum[b] = red[0] + red[1] + red[2] + red[3];
}

// row_ptr from (bucket_sum scan) + (local counts scan); one kernel
__global__ __launch_bounds__(256) void row_ptr_build(const int* __restrict__ counts,
                                                     const int* __restrict__ bucket_sum,
                                                     int* __restrict__ row_ptr) {
    __shared__ int bs[NB];
    __shared__ int loc[256];
    const int b = blockIdx.x, tid = threadIdx.x;
    bs[tid] = bucket_sum[tid];                    // NB == 256 == blockDim
    __syncthreads();
    for (int off = 1; off < 256; off <<= 1) {     // inclusive scan of bucket sums
        const int w = (tid >= off) ? bs[tid - off] : 0;
        __syncthreads();
        bs[tid] += w;
        __syncthreads();
    }
    const int bucket_off = bs[b] - bucket_sum[b]; // exclusive offset of this bucket
    const int node = b * BUCKET_NODES + tid;
    const int c = (tid < BUCKET_NODES && node < N_NODES) ? counts[node] : 0;
    loc[tid] = c;
    __syncthreads();
    for (int off = 1; off < 256; off <<= 1) {     // inclusive scan of local counts
        const int w = (tid >= off) ? loc[tid - off] : 0;
        __syncthreads();
        loc[tid] += w;
        __syncthreads();
    }
    if (tid < BUCKET_NODES && node < N_NODES) row_ptr[node] = bucket_off + loc[tid] - c;
    if (b == 0 && tid == 0) row_ptr[N_NODES] = N_EDGES;
}

__global__ __launch_bounds__(256) void bucket_to_csr(const int2* __restrict__ staging,
                                                     const int* __restrict__ offs,
                                                     const int* __restrict__ row_ptr,
                                                     int* __restrict__ csr_src) {
    __shared__ int cur[BUCKET_NODES];
    const int b = blockIdx.x;
    for (int i = threadIdx.x; i < BUCKET_NODES; i += 256) {
        const int node = b * BUCKET_NODES + i;
        cur[i] = (node < N_NODES) ? row_ptr[node] : 0;
    }
    __syncthreads();
    const int s0 = offs[b * NBLK];
    const int s1 = (b == NB - 1) ? N_EDGES : offs[(b + 1) * NBLK];
    for (int i = s0 + threadIdx.x; i < s1; i += 256) {
        const int2 e = staging[i];
        const int pos = atomicAdd(&cur[e.y - b * BUCKET_NODES], 1);
        csr_src[pos] = e.x;
    }
}

// ============================================================
// K1: z = h @ W.T + b — wave owns 8 rows, lane = output column.
//     z stored as bf16.
// ============================================================
#define NL_ROWS 8
__global__ __launch_bounds__(256) void node_linear_gemm(
    const float* __restrict__ h, ushort_t* __restrict__ zb,
    const float* __restrict__ W, const float* __restrict__ b,
    const float* __restrict__ a, const float* __restrict__ ab,
    float* __restrict__ s_src, float* __restrict__ s_dst)
{
    __shared__ float Wt[64 * 65];           // Wt[k*65 + j] = W[j*64 + k]
    for (int idx = threadIdx.x; idx < D * D; idx += 256) {
        const int j = idx >> 6, k = idx & 63;
        Wt[k * 65 + j] = W[idx];
    }
    __syncthreads();

    const int lane = threadIdx.x & 63;
    const int wv   = __builtin_amdgcn_readfirstlane(threadIdx.x >> 6);
    const int row0 = (blockIdx.x * 4 + wv) * NL_ROWS;
    if (row0 >= N_NODES) return;

    const float bj  = b[lane];
    const float alo = a[lane];
    const float ahi = a[64 + lane];

    const float* hr[NL_ROWS];
    #pragma unroll
    for (int r = 0; r < NL_ROWS; ++r) hr[r] = h + (size_t)(row0 + r) * D;

    float acc[NL_ROWS];
    #pragma unroll
    for (int r = 0; r < NL_ROWS; ++r) acc[r] = bj;

    #pragma unroll 4
    for (int k = 0; k < D; ++k) {
        const float wkj = Wt[k * 65 + lane];
        #pragma unroll
        for (int r = 0; r < NL_ROWS; ++r)
            acc[r] = fmaf(hr[r][k], wkj, acc[r]);
    }

    #pragma unroll
    for (int r = 0; r < NL_ROWS; ++r) {
        zb[(size_t)(row0 + r) * D + lane] = f32_to_bf16(acc[r]);
        float u = acc[r] * alo;
        float v = acc[r] * ahi;
        #pragma unroll
        for (int off = 32; off >= 1; off >>= 1) {
            u += __shfl_xor(u, off, 64);
            v += __shfl_xor(v, off, 64);
        }
        if (lane == 0) { s_src[row0 + r] = u; s_dst[row0 + r] = v + ab[0]; }
    }
}

// ============================================================
// K2: FUSED softmax + weighted gather (+ReLU).
//   phase A: 4 nodes/wave, 16 lanes/node — online (m, den) only.
//   phase B: per node, 64-lane paired bf16 gather; w recomputed
//            inline as exp(e-m)/den (csr/s_src lines L1-hot from A).
//   No intermediate global buffers, no shuffles in gather loop.
// ============================================================
template<bool RELU>
__global__ __launch_bounds__(256) void fused_softmax_gather(
    const int* __restrict__ row_ptr, const int* __restrict__ csr_src,
    const float* __restrict__ s_src, const float* __restrict__ s_dst,
    const ushort_t* __restrict__ zb, float* __restrict__ out)
{
    __shared__ int2 sh[4][64];
    const int lane = threadIdx.x & 63;
    const int wv   = threadIdx.x >> 6;
    const int g    = lane >> 4;                    // node group 0..3
    const int sl   = lane & 15;
    const int node0 = (blockIdx.x * 4 + wv) * 4;   // 50000 % 4 == 0, grid exact
    if (node0 >= N_NODES) return;
    const int mynode = node0 + g;

    // ---- phase A: online (m, den) for mynode ----
    const int beg = row_ptr[mynode];
    const int end = row_ptr[mynode + 1];
    const float sd = s_dst[mynode];
    float m = -INFINITY, den = 0.f;
    for (int base = beg; base < end; base += 16) {
        const int n = min(16, end - base);
        float e = -INFINITY;
        if (sl < n) {
            const int s = csr_src[base + sl];
            e = s_src[s] + sd;
            e = e > 0.f ? e : 0.01f * e;           // leaky_relu
        }
        float mc = e;
        #pragma unroll
        for (int off = 8; off >= 1; off >>= 1) mc = fmaxf(mc, __shfl_xor(mc, off, 64));
        if (mc > m) { den *= __expf(m - mc); m = mc; }
        float ex = (sl < n) ? __expf(e - m) : 0.f;
        #pragma unroll
        for (int off = 8; off >= 1; off >>= 1) ex += __shfl_xor(ex, off, 64);
        den += ex;
    }
    const float invden = (den > 0.f) ? 1.f / den : 0.f;

    // ---- phase B: paired gather per node ----
    const int half = lane >> 5;          // 0: even edges, 1: odd edges
    const int fl   = lane & 31;          // feature pair (2fl, 2fl+1)
    #pragma unroll
    for (int q = 0; q < 4; ++q) {
        const int nq    = node0 + q;
        const int begq  = __shfl(beg, q * 16, 64);
        const int endq  = __shfl(end, q * 16, 64);
        const float mq  = __shfl(m, q * 16, 64);
        const float ivq = __shfl(invden, q * 16, 64);
        const float sdq = __shfl(sd, q * 16, 64);

        float2 acc[8];
        #pragma unroll
        for (int p = 0; p < 8; ++p) acc[p] = make_float2(0.f, 0.f);

        for (int base = begq; base < endq; base += 64) {
            const int n = min(64, endq - base);
            int2 ws = make_int2(0, 0);
            if (lane < n) {
                const int s = csr_src[base + lane];
                float e = s_src[s] + sdq;
                e = e > 0.f ? e : 0.01f * e;
                ws = make_int2(__float_as_int(__expf(e - mq) * ivq), s);
            }
            sh[wv][lane] = ws;                     // wave-synchronous, no barrier
            for (int t = 0; t < n; t += 16) {
                #pragma unroll
                for (int p = 0; p < 8; ++p) {
                    const int ei = t + 2 * p + half;
                    const int2 w2 = sh[wv][ei];
                    const float w = __int_as_float(w2.x);   // 0 for pad slots
                    const unsigned u = *(const unsigned*)&zb[(size_t)w2.y * D + 2 * fl];
                    acc[p].x = fmaf(w, __uint_as_float(u << 16), acc[p].x);
                    acc[p].y = fmaf(w, __uint_as_float(u & 0xffff0000u), acc[p].y);
                }
            }
        }
        float2 tot = make_float2(0.f, 0.f);
        #pragma unroll
        for (int p = 0; p < 8; ++p) { tot.x += acc[p].x; tot.y += acc[p].y; }
        tot.x += __shfl_xor(tot.x, 32, 64);
        tot.y += __shfl_xor(tot.y, 32, 64);
        if (RELU) { tot.x = fmaxf(tot.x, 0.f); tot.y = fmaxf(tot.y, 0.f); }
        if (half == 0)
            *(float2*)&out[(size_t)nq * D + 2 * fl] = tot;
    }
}

// ============================================================
extern "C" void kernel_launch(void* const* d_in, const int* in_sizes, int n_in,
                              void* d_out, int out_size, void* d_ws, size_t ws_size,
                              hipStream_t stream) {
    const float* x   = (const float*)d_in[0];
    const int*   src = (const int*)d_in[1];
    const int*   dst = (const int*)d_in[2];
    float* out = (float*)d_out;

    // ---- workspace carve-out (256B-aligned slots, ~17 MB) ----
    char* wp = (char*)d_ws;
    auto alloc = [&](size_t bytes) -> void* {
        void* p = (void*)wp;
        wp += (bytes + 255) & ~(size_t)255;
        return p;
    };
    ushort_t* zb      = (ushort_t*)alloc((size_t)N_NODES * D * sizeof(ushort_t));
    float* s_src      = (float*)alloc((size_t)N_NODES * sizeof(float));
    float* s_dst      = (float*)alloc((size_t)N_NODES * sizeof(float));
    int*   counts     = (int*)alloc((size_t)N_NODES * sizeof(int));
    int*   row_ptr    = (int*)alloc((size_t)(N_NODES + 1) * sizeof(int));
    int*   csr_src    = (int*)alloc((size_t)N_EDGES * sizeof(int));
    int*   partB      = (int*)alloc(64 * sizeof(int));
    int*   bucket_sum = (int*)alloc((size_t)NB * sizeof(int));
    int*   Acnt       = (int*)alloc((size_t)NB * NBLK * sizeof(int));
    int*   offs       = (int*)alloc((size_t)NB * NBLK * sizeof(int));
    int2*  staging    = (int2*)alloc((size_t)N_EDGES * sizeof(int2));
    (void)ws_size;

    // ---- bucketed CSR build: 7 dispatches, zero global atomics ----
    bucket_hist<<<NBLK, 256, 0, stream>>>(dst, Acnt);
    scan_partial_g<NB * NBLK><<<64, 256, 0, stream>>>(Acnt, partB);
    scan_write_i<NB * NBLK, 64><<<64, 256, 0, stream>>>(Acnt, partB, offs);
    bucket_scatter<<<NBLK, 256, 0, stream>>>(src, dst, offs, staging);
    node_counts<<<NB, 256, 0, stream>>>(staging, offs, counts, bucket_sum);
    row_ptr_build<<<NB, 256, 0, stream>>>(counts, bucket_sum, row_ptr);
    bucket_to_csr<<<NB, 256, 0, stream>>>(staging, offs, row_ptr, csr_src);

    const int grid_k1 = (N_NODES + 4 * NL_ROWS - 1) / (4 * NL_ROWS);  // 1563
    const int grid_fg = N_NODES / 16;                                  // 3125 exact

    for (int layer = 0; layer < 3; ++layer) {
        const float* W  = (const float*)d_in[3 + 4 * layer];
        const float* b  = (const float*)d_in[4 + 4 * layer];
        const float* a  = (const float*)d_in[5 + 4 * layer];
        const float* ab = (const float*)d_in[6 + 4 * layer];
        const float* hin = (layer == 0) ? x : out;   // d_out doubles as h buffer

        node_linear_gemm<<<grid_k1, 256, 0, stream>>>(hin, zb, W, b, a, ab, s_src, s_dst);
        if (layer < 2) {
            fused_softmax_gather<true ><<<grid_fg, 256, 0, stream>>>(row_ptr, csr_src, s_src, s_dst, zb, out);
        } else {
            fused_softmax_gather<false><<<grid_fg, 256, 0, stream>>>(row_ptr, csr_src, s_src, s_dst, zb, out);
        }
    }
}

// Round 11
// 197.655 us; speedup vs baseline: 1.1141x; 1.0097x over previous
//
#include <hip/hip_runtime.h>
#include <math.h>

#define N_NODES 50000
#define N_EDGES 800000
#define D 64

#define NB 256                    // dst buckets
#define NBLK 256                  // blocks in bucket hist/scatter
#define BUCKET_NODES 196          // ceil(50000/256); 256*196 = 50176
#define TILE 3125                 // 800000 / 256 exactly

typedef unsigned short ushort_t;

__device__ __forceinline__ ushort_t f32_to_bf16(float f) {
    unsigned u = __float_as_uint(f);
    u += 0x7fffu + ((u >> 16) & 1u);      // round-to-nearest-even
    return (ushort_t)(u >> 16);
}

// ============================================================
// scan pass 1: per-1024-tile sums
// ============================================================
template<int N>
__global__ void scan_partial_g(const int* __restrict__ in, int* __restrict__ partials) {
    const int base = blockIdx.x * 1024 + threadIdx.x * 4;
    int4 c = make_int4(0, 0, 0, 0);
    if (base + 3 < N) c = *(const int4*)&in[base];
    else { int* cp = (int*)&c; for (int j = 0; j < 4; ++j) if (base + j < N) cp[j] = in[base + j]; }
    int s = c.x + c.y + c.z + c.w;
    #pragma unroll
    for (int off = 32; off >= 1; off >>= 1) s += __shfl_xor(s, off, 64);
    __shared__ int red[4];
    if ((threadIdx.x & 63) == 0) red[threadIdx.x >> 6] = s;
    __syncthreads();
    if (threadIdx.x == 0) partials[blockIdx.x] = red[0] + red[1] + red[2] + red[3];
}

// ============================================================
// scan pass 2 (fused): each block re-scans the <=64 raw partials
// in wave 0, then does its local scan + write.
// ============================================================
template<int N, int NT>
__global__ void scan_write_i(const int* __restrict__ in, const int* __restrict__ partials_raw,
                             int* __restrict__ out) {
    __shared__ int toff;
    __shared__ int sh[256];
    const int tid = threadIdx.x;
    if (tid < 64) {
        const int v = (tid < NT) ? partials_raw[tid] : 0;
        int inc = v;
        #pragma unroll
        for (int off = 1; off < 64; off <<= 1) {
            const int w = __shfl_up(inc, off, 64);
            if (tid >= off) inc += w;
        }
        if (tid == blockIdx.x) toff = inc - v;   // exclusive tile offset (blockIdx < 64)
    }
    const int base = blockIdx.x * 1024 + tid * 4;
    int4 c = make_int4(0, 0, 0, 0);
    if (base + 3 < N) c = *(const int4*)&in[base];
    else { int* cp = (int*)&c; for (int j = 0; j < 4; ++j) if (base + j < N) cp[j] = in[base + j]; }
    const int s = c.x + c.y + c.z + c.w;
    sh[tid] = s;
    __syncthreads();
    for (int off = 1; off < 256; off <<= 1) {
        const int w = (tid >= off) ? sh[tid - off] : 0;
        __syncthreads();
        sh[tid] += w;
        __syncthreads();
    }
    int run = toff + sh[tid] - s;
    const int* cp = (const int*)&c;
    int rp[4];
    #pragma unroll
    for (int j = 0; j < 4; ++j) { rp[j] = run; run += cp[j]; }
    if (base + 3 < N) *(int4*)&out[base] = make_int4(rp[0], rp[1], rp[2], rp[3]);
    else for (int j = 0; j < 4; ++j) if (base + j < N) out[base + j] = rp[j];
}

// ============================================================
// Bucketed CSR build — no global atomics, XCD-local final writes
// ============================================================
__global__ __launch_bounds__(256) void bucket_hist(const int* __restrict__ dst,
                                                   int* __restrict__ Acnt) {
    __shared__ int hist[NB];
    for (int i = threadIdx.x; i < NB; i += 256) hist[i] = 0;
    __syncthreads();
    const int base = blockIdx.x * TILE;
    for (int i = threadIdx.x; i < TILE; i += 256)
        atomicAdd(&hist[dst[base + i] / BUCKET_NODES], 1);
    __syncthreads();
    for (int bk = threadIdx.x; bk < NB; bk += 256)
        Acnt[bk * NBLK + blockIdx.x] = hist[bk];
}

__global__ __launch_bounds__(256) void bucket_scatter(const int* __restrict__ src,
                                                      const int* __restrict__ dst,
                                                      const int* __restrict__ offs,
                                                      int2* __restrict__ staging) {
    __shared__ int cur[NB];
    for (int i = threadIdx.x; i < NB; i += 256) cur[i] = offs[i * NBLK + blockIdx.x];
    __syncthreads();
    const int base = blockIdx.x * TILE;
    for (int i = threadIdx.x; i < TILE; i += 256) {
        const int s = src[base + i], d = dst[base + i];
        const int pos = atomicAdd(&cur[d / BUCKET_NODES], 1);
        staging[pos] = make_int2(s, d);
    }
}

// node histogram per bucket (LDS) + per-bucket total
__global__ __launch_bounds__(256) void node_counts(const int2* __restrict__ staging,
                                                   const int* __restrict__ offs,
                                                   int* __restrict__ counts,
                                                   int* __restrict__ bucket_sum) {
    __shared__ int cnt[BUCKET_NODES];
    __shared__ int red[4];
    const int b = blockIdx.x, tid = threadIdx.x;
    for (int i = tid; i < BUCKET_NODES; i += 256) cnt[i] = 0;
    __syncthreads();
    const int s0 = offs[b * NBLK];
    const int s1 = (b == NB - 1) ? N_EDGES : offs[(b + 1) * NBLK];
    for (int i = s0 + tid; i < s1; i += 256)
        atomicAdd(&cnt[staging[i].y - b * BUCKET_NODES], 1);
    __syncthreads();
    for (int i = tid; i < BUCKET_NODES; i += 256) {
        const int node = b * BUCKET_NODES + i;
        if (node < N_NODES) counts[node] = cnt[i];
    }
    int s = (tid < BUCKET_NODES) ? cnt[tid] : 0;
    #pragma unroll
    for (int off = 32; off >= 1; off >>= 1) s += __shfl_xor(s, off, 64);
    if ((tid & 63) == 0) red[tid >> 6] = s;
    __syncthreads();
    if (tid == 0) bucket_sum[b] = red[0] + red[1] + red[2] + red[3];
}

// row_ptr from (bucket_sum scan) + (local counts scan); one kernel
__global__ __launch_bounds__(256) void row_ptr_build(const int* __restrict__ counts,
                                                     const int* __restrict__ bucket_sum,
                                                     int* __restrict__ row_ptr) {
    __shared__ int bs[NB];
    __shared__ int loc[256];
    const int b = blockIdx.x, tid = threadIdx.x;
    bs[tid] = bucket_sum[tid];                    // NB == 256 == blockDim
    __syncthreads();
    for (int off = 1; off < 256; off <<= 1) {     // inclusive scan of bucket sums
        const int w = (tid >= off) ? bs[tid - off] : 0;
        __syncthreads();
        bs[tid] += w;
        __syncthreads();
    }
    const int bucket_off = bs[b] - bucket_sum[b]; // exclusive offset of this bucket
    const int node = b * BUCKET_NODES + tid;
    const int c = (tid < BUCKET_NODES && node < N_NODES) ? counts[node] : 0;
    loc[tid] = c;
    __syncthreads();
    for (int off = 1; off < 256; off <<= 1) {     // inclusive scan of local counts
        const int w = (tid >= off) ? loc[tid - off] : 0;
        __syncthreads();
        loc[tid] += w;
        __syncthreads();
    }
    if (tid < BUCKET_NODES && node < N_NODES) row_ptr[node] = bucket_off + loc[tid] - c;
    if (b == 0 && tid == 0) row_ptr[N_NODES] = N_EDGES;
}

__global__ __launch_bounds__(256) void bucket_to_csr(const int2* __restrict__ staging,
                                                     const int* __restrict__ offs,
                                                     const int* __restrict__ row_ptr,
                                                     int* __restrict__ csr_src) {
    __shared__ int cur[BUCKET_NODES];
    const int b = blockIdx.x;
    for (int i = threadIdx.x; i < BUCKET_NODES; i += 256) {
        const int node = b * BUCKET_NODES + i;
        cur[i] = (node < N_NODES) ? row_ptr[node] : 0;
    }
    __syncthreads();
    const int s0 = offs[b * NBLK];
    const int s1 = (b == NB - 1) ? N_EDGES : offs[(b + 1) * NBLK];
    for (int i = s0 + threadIdx.x; i < s1; i += 256) {
        const int2 e = staging[i];
        const int pos = atomicAdd(&cur[e.y - b * BUCKET_NODES], 1);
        csr_src[pos] = e.x;
    }
}

// ============================================================
// K1: z = h @ W.T + b — wave owns 8 rows, lane = output column.
//     z stored as bf16.
// ============================================================
#define NL_ROWS 8
__global__ __launch_bounds__(256) void node_linear_gemm(
    const float* __restrict__ h, ushort_t* __restrict__ zb,
    const float* __restrict__ W, const float* __restrict__ b,
    const float* __restrict__ a, const float* __restrict__ ab,
    float* __restrict__ s_src, float* __restrict__ s_dst)
{
    __shared__ float Wt[64 * 65];           // Wt[k*65 + j] = W[j*64 + k]
    for (int idx = threadIdx.x; idx < D * D; idx += 256) {
        const int j = idx >> 6, k = idx & 63;
        Wt[k * 65 + j] = W[idx];
    }
    __syncthreads();

    const int lane = threadIdx.x & 63;
    const int wv   = __builtin_amdgcn_readfirstlane(threadIdx.x >> 6);
    const int row0 = (blockIdx.x * 4 + wv) * NL_ROWS;
    if (row0 >= N_NODES) return;

    const float bj  = b[lane];
    const float alo = a[lane];
    const float ahi = a[64 + lane];

    const float* hr[NL_ROWS];
    #pragma unroll
    for (int r = 0; r < NL_ROWS; ++r) hr[r] = h + (size_t)(row0 + r) * D;

    float acc[NL_ROWS];
    #pragma unroll
    for (int r = 0; r < NL_ROWS; ++r) acc[r] = bj;

    #pragma unroll 4
    for (int k = 0; k < D; ++k) {
        const float wkj = Wt[k * 65 + lane];
        #pragma unroll
        for (int r = 0; r < NL_ROWS; ++r)
            acc[r] = fmaf(hr[r][k], wkj, acc[r]);
    }

    #pragma unroll
    for (int r = 0; r < NL_ROWS; ++r) {
        zb[(size_t)(row0 + r) * D + lane] = f32_to_bf16(acc[r]);
        float u = acc[r] * alo;
        float v = acc[r] * ahi;
        #pragma unroll
        for (int off = 32; off >= 1; off >>= 1) {
            u += __shfl_xor(u, off, 64);
            v += __shfl_xor(v, off, 64);
        }
        if (lane == 0) { s_src[row0 + r] = u; s_dst[row0 + r] = v + ab[0]; }
    }
}

// ============================================================
// K2: FUSED softmax + weighted gather (+ReLU).
//   phase A: 4 nodes/wave, 16 lanes/node — online (m, den) only.
//   phase B: all 4 nodes' weight tables staged in DISJOINT LDS
//            regions, then ONE interleaved gather loop issuing
//            8 independent paired loads (2 edges × 4 nodes) per
//            step — ~4x memory-level parallelism vs sequential q.
// ============================================================
template<bool RELU>
__global__ __launch_bounds__(256) void fused_softmax_gather(
    const int* __restrict__ row_ptr, const int* __restrict__ csr_src,
    const float* __restrict__ s_src, const float* __restrict__ s_dst,
    const ushort_t* __restrict__ zb, float* __restrict__ out)
{
    __shared__ int2 sh[4][4][64];                  // [wave][node q][slot] = 8 KB
    const int lane = threadIdx.x & 63;
    const int wv   = threadIdx.x >> 6;
    const int g    = lane >> 4;                    // node group 0..3
    const int sl   = lane & 15;
    const int node0 = (blockIdx.x * 4 + wv) * 4;   // 50000 % 16 == 0, grid exact
    if (node0 >= N_NODES) return;
    const int mynode = node0 + g;

    // ---- phase A: online (m, den) for mynode (16 lanes each) ----
    const int beg = row_ptr[mynode];
    const int end = row_ptr[mynode + 1];
    const float sd = s_dst[mynode];
    float m = -INFINITY, den = 0.f;
    for (int base = beg; base < end; base += 16) {
        const int n = min(16, end - base);
        float e = -INFINITY;
        if (sl < n) {
            const int s = csr_src[base + sl];
            e = s_src[s] + sd;
            e = e > 0.f ? e : 0.01f * e;           // leaky_relu
        }
        float mc = e;
        #pragma unroll
        for (int off = 8; off >= 1; off >>= 1) mc = fmaxf(mc, __shfl_xor(mc, off, 64));
        if (mc > m) { den *= __expf(m - mc); m = mc; }
        float ex = (sl < n) ? __expf(e - m) : 0.f;
        #pragma unroll
        for (int off = 8; off >= 1; off >>= 1) ex += __shfl_xor(ex, off, 64);
        den += ex;
    }
    const float invden = (den > 0.f) ? 1.f / den : 0.f;

    // ---- broadcast per-node params to the whole wave ----
    int begq[4], endq[4];
    float mq[4], ivq[4], sdq[4];
    #pragma unroll
    for (int q = 0; q < 4; ++q) {
        begq[q] = __shfl(beg, q * 16, 64);
        endq[q] = __shfl(end, q * 16, 64);
        mq[q]   = __shfl(m, q * 16, 64);
        ivq[q]  = __shfl(invden, q * 16, 64);
        sdq[q]  = __shfl(sd, q * 16, 64);
    }
    int maxdeg = 0;
    #pragma unroll
    for (int q = 0; q < 4; ++q) maxdeg = max(maxdeg, endq[q] - begq[q]);

    // ---- phase B: interleaved 4-node gather ----
    const int half = lane >> 5;          // 0: even edges, 1: odd edges
    const int fl   = lane & 31;          // feature pair (2fl, 2fl+1)
    float2 acc[4][2];
    #pragma unroll
    for (int q = 0; q < 4; ++q) {
        acc[q][0] = make_float2(0.f, 0.f);
        acc[q][1] = make_float2(0.f, 0.f);
    }

    for (int c = 0; c < maxdeg; c += 64) {
        // stage all 4 nodes' (w, src) into disjoint LDS slabs
        #pragma unroll
        for (int q = 0; q < 4; ++q) {
            int2 ws = make_int2(0, 0);             // pad: weight 0, src 0 (L1-hot row)
            const int i = begq[q] + c + lane;
            if (i < endq[q]) {
                const int s = csr_src[i];
                float e = s_src[s] + sdq[q];
                e = e > 0.f ? e : 0.01f * e;
                ws = make_int2(__float_as_int(__expf(e - mq[q]) * ivq[q]), s);
            }
            sh[wv][q][lane] = ws;                  // wave-synchronous
        }
        const int n = min(64, maxdeg - c);
        for (int t = 0; t < n; t += 4) {           // 4 edges/node/iter
            #pragma unroll
            for (int q = 0; q < 4; ++q) {
                const int2 wa = sh[wv][q][t + half];
                const int2 wb = sh[wv][q][t + 2 + half];
                const unsigned ua = *(const unsigned*)&zb[(size_t)wa.y * D + 2 * fl];
                const unsigned ub = *(const unsigned*)&zb[(size_t)wb.y * D + 2 * fl];
                const float fa = __int_as_float(wa.x);
                const float fb = __int_as_float(wb.x);
                acc[q][0].x = fmaf(fa, __uint_as_float(ua << 16), acc[q][0].x);
                acc[q][0].y = fmaf(fa, __uint_as_float(ua & 0xffff0000u), acc[q][0].y);
                acc[q][1].x = fmaf(fb, __uint_as_float(ub << 16), acc[q][1].x);
                acc[q][1].y = fmaf(fb, __uint_as_float(ub & 0xffff0000u), acc[q][1].y);
            }
        }
    }
    #pragma unroll
    for (int q = 0; q < 4; ++q) {
        float2 tot = make_float2(acc[q][0].x + acc[q][1].x,
                                 acc[q][0].y + acc[q][1].y);
        tot.x += __shfl_xor(tot.x, 32, 64);        // merge even/odd halves
        tot.y += __shfl_xor(tot.y, 32, 64);
        if (RELU) { tot.x = fmaxf(tot.x, 0.f); tot.y = fmaxf(tot.y, 0.f); }
        if (half == 0)
            *(float2*)&out[(size_t)(node0 + q) * D + 2 * fl] = tot;
    }
}

// ============================================================
extern "C" void kernel_launch(void* const* d_in, const int* in_sizes, int n_in,
                              void* d_out, int out_size, void* d_ws, size_t ws_size,
                              hipStream_t stream) {
    const float* x   = (const float*)d_in[0];
    const int*   src = (const int*)d_in[1];
    const int*   dst = (const int*)d_in[2];
    float* out = (float*)d_out;

    // ---- workspace carve-out (256B-aligned slots, ~17 MB) ----
    char* wp = (char*)d_ws;
    auto alloc = [&](size_t bytes) -> void* {
        void* p = (void*)wp;
        wp += (bytes + 255) & ~(size_t)255;
        return p;
    };
    ushort_t* zb      = (ushort_t*)alloc((size_t)N_NODES * D * sizeof(ushort_t));
    float* s_src      = (float*)alloc((size_t)N_NODES * sizeof(float));
    float* s_dst      = (float*)alloc((size_t)N_NODES * sizeof(float));
    int*   counts     = (int*)alloc((size_t)N_NODES * sizeof(int));
    int*   row_ptr    = (int*)alloc((size_t)(N_NODES + 1) * sizeof(int));
    int*   csr_src    = (int*)alloc((size_t)N_EDGES * sizeof(int));
    int*   partB      = (int*)alloc(64 * sizeof(int));
    int*   bucket_sum = (int*)alloc((size_t)NB * sizeof(int));
    int*   Acnt       = (int*)alloc((size_t)NB * NBLK * sizeof(int));
    int*   offs       = (int*)alloc((size_t)NB * NBLK * sizeof(int));
    int2*  staging    = (int2*)alloc((size_t)N_EDGES * sizeof(int2));
    (void)ws_size;

    // ---- bucketed CSR build: 7 dispatches, zero global atomics ----
    bucket_hist<<<NBLK, 256, 0, stream>>>(dst, Acnt);
    scan_partial_g<NB * NBLK><<<64, 256, 0, stream>>>(Acnt, partB);
    scan_write_i<NB * NBLK, 64><<<64, 256, 0, stream>>>(Acnt, partB, offs);
    bucket_scatter<<<NBLK, 256, 0, stream>>>(src, dst, offs, staging);
    node_counts<<<NB, 256, 0, stream>>>(staging, offs, counts, bucket_sum);
    row_ptr_build<<<NB, 256, 0, stream>>>(counts, bucket_sum, row_ptr);
    bucket_to_csr<<<NB, 256, 0, stream>>>(staging, offs, row_ptr, csr_src);

    const int grid_k1 = (N_NODES + 4 * NL_ROWS - 1) / (4 * NL_ROWS);  // 1563
    const int grid_fg = N_NODES / 16;                                  // 3125 exact

    for (int layer = 0; layer < 3; ++layer) {
        const float* W  = (const float*)d_in[3 + 4 * layer];
        const float* b  = (const float*)d_in[4 + 4 * layer];
        const float* a  = (const float*)d_in[5 + 4 * layer];
        const float* ab = (const float*)d_in[6 + 4 * layer];
        const float* hin = (layer == 0) ? x : out;   // d_out doubles as h buffer

        node_linear_gemm<<<grid_k1, 256, 0, stream>>>(hin, zb, W, b, a, ab, s_src, s_dst);
        if (layer < 2) {
            fused_softmax_gather<true ><<<grid_fg, 256, 0, stream>>>(row_ptr, csr_src, s_src, s_dst, zb, out);
        } else {
            fused_softmax_gather<false><<<grid_fg, 256, 0, stream>>>(row_ptr, csr_src, s_src, s_dst, zb, out);
        }
    }
}